// Round 13
// baseline (236.376 us; speedup 1.0000x reference)
//
#include <hip/hip_runtime.h>
#include <hip/hip_bf16.h>

#define N_NODES 100000
#define N_EDGES 3200000
#define IN_F 256
#define OUT_F 128

#define RPB 128           // rows per bucket
#define NBIN 782          // ceil(100000/128); bin = row >> 7
#define NBC  896          // sort-chunk blocks
#define CHUNK 3572        // edges per chunk (896*3572 >= 3.2M, %4==0)
#define GEMM_BLOCKS 782   // (N_NODES + 127) / 128
#define CONV_BLOCKS 16
#define BPTC 4            // bins per thread in pass C local scan
#define CAP 4608          // LDS edge capacity per bucket (mean 4096, sigma ~64)

typedef __attribute__((ext_vector_type(8))) short bf16x8;
typedef __attribute__((ext_vector_type(4))) float f32x4;

union U4BF { uint4 u; bf16x8 v; };

__device__ inline unsigned short f2bf(float f) {
    return __bfloat16_as_ushort(__float2bfloat16(f));
}
__device__ inline unsigned pk2(float a, float b) {
    unsigned la = __bfloat16_as_ushort(__float2bfloat16(a));
    unsigned lb = __bfloat16_as_ushort(__float2bfloat16(b));
    return la | (lb << 16);
}

// ---------- Kernel 1: fused w-conversion (blocks 0..15) + coarse hist ----------
__global__ __launch_bounds__(256) void conv_hist_kernel(
    const float* __restrict__ w, uint4* __restrict__ wbfF,
    const int* __restrict__ erow, int* __restrict__ cntmat)
{
    __shared__ int lhist[NBIN];
    const int t = threadIdx.x;

    if (blockIdx.x < CONV_BLOCKS) {
        int tid = blockIdx.x * 256 + t;   // 0..4095
        int ks = tid >> 9;
        int fn = (tid >> 6) & 7;
        int l  = tid & 63;
        int c  = fn * 16 + (l & 15);
        int k0 = ks * 32 + (l >> 4) * 8;
        const float* wp = w + (size_t)k0 * OUT_F + c;
        uint4 u;
        u.x = pk2(wp[0 * OUT_F], wp[1 * OUT_F]);
        u.y = pk2(wp[2 * OUT_F], wp[3 * OUT_F]);
        u.z = pk2(wp[4 * OUT_F], wp[5 * OUT_F]);
        u.w = pk2(wp[6 * OUT_F], wp[7 * OUT_F]);
        wbfF[tid] = u;
    } else {
        const int b = blockIdx.x - CONV_BLOCKS;
        for (int i = t; i < NBIN; i += 256) lhist[i] = 0;
        __syncthreads();

        const int base = b * CHUNK;
        const int end  = min(base + CHUNK, N_EDGES);
        for (int i = base + t * 4; i < end; i += 1024) {
            int4 r = *(const int4*)(erow + i);
            atomicAdd(&lhist[r.x >> 7], 1);
            atomicAdd(&lhist[r.y >> 7], 1);
            atomicAdd(&lhist[r.z >> 7], 1);
            atomicAdd(&lhist[r.w >> 7], 1);
        }
        __syncthreads();

        int* dst = cntmat + (size_t)b * NBIN;
        for (int j = t; j < NBIN; j += 256) dst[j] = lhist[j];
    }
}

// ---------- Pass B: per-bin exclusive scan over 896 chunk-blocks ----------
__global__ __launch_bounds__(256) void pass_b_kernel(
    const int* __restrict__ cntmat, int* __restrict__ blockbase,
    int* __restrict__ tot)
{
    __shared__ int sh[256];
    const int t = threadIdx.x;
    const int j = blockIdx.x;
    int c[4];
    int ps = 0;
#pragma unroll
    for (int i = 0; i < 4; ++i) {
        int bb = 4 * t + i;
        c[i] = (bb < NBC) ? cntmat[(size_t)bb * NBIN + j] : 0;
        ps += c[i];
    }
    sh[t] = ps;
    __syncthreads();
    for (int off = 1; off < 256; off <<= 1) {
        int add = (t >= off) ? sh[t - off] : 0;
        __syncthreads();
        sh[t] += add;
        __syncthreads();
    }
    int excl = sh[t] - ps;
#pragma unroll
    for (int i = 0; i < 4; ++i) {
        int bb = 4 * t + i;
        if (bb < NBC) { blockbase[(size_t)bb * NBIN + j] = excl; excl += c[i]; }
    }
    if (t == 255) tot[j] = sh[255];
}

// ---------- Pass B2: exclusive scan of 782 bucket totals ----------
__global__ __launch_bounds__(512) void pass_b2_kernel(
    const int* __restrict__ tot, int* __restrict__ bucket_base)
{
    __shared__ int sh[512];
    const int t = threadIdx.x;
    const int i0 = 2 * t, i1 = 2 * t + 1;
    int v0 = (i0 < NBIN) ? tot[i0] : 0;
    int v1 = (i1 < NBIN) ? tot[i1] : 0;
    int ps = v0 + v1;
    sh[t] = ps;
    __syncthreads();
    for (int off = 1; off < 512; off <<= 1) {
        int add = (t >= off) ? sh[t - off] : 0;
        __syncthreads();
        sh[t] += add;
        __syncthreads();
    }
    int excl = sh[t] - ps;
    if (i0 <= NBIN) bucket_base[i0] = excl;
    if (i1 <= NBIN) bucket_base[i1] = excl + v0;     // i1==NBIN -> N_EDGES
}

// ---------- Kernel 4: fused GEMM (blocks 0..781) + pass C (782..1677) ----------
__global__ __launch_bounds__(256) void gemm_passc_kernel(
    const float* __restrict__ x, const uint4* __restrict__ wbfF,
    unsigned short* __restrict__ h,
    const int* __restrict__ erow, const int* __restrict__ ecol,
    const float* __restrict__ eval_, const int* __restrict__ cntmat,
    const int* __restrict__ blockbase, const int* __restrict__ bucket_base,
    int2* __restrict__ tmp)
{
    __shared__ __align__(16) char smem[65536];
    const int t = threadIdx.x;

    if (blockIdx.x < GEMM_BLOCKS) {
        // ================= GEMM path =================
        uint4* bsh = (uint4*)smem;
        const int lane = t & 63;
        const int wid  = t >> 6;
        const int brow = blockIdx.x * 128;
        const int ln   = lane & 15;
        const int kb   = lane >> 4;

#pragma unroll
        for (int i = 0; i < 16; ++i) bsh[i * 256 + t] = wbfF[i * 256 + t];

        int r0 = brow + wid * 32 + ln;
        int r1 = r0 + 16;
        const float* a0p = x + (size_t)(r0 < N_NODES ? r0 : N_NODES - 1) * IN_F;
        const float* a1p = x + (size_t)(r1 < N_NODES ? r1 : N_NODES - 1) * IN_F;

        f32x4 acc[2][8] = {};
        __syncthreads();

#pragma unroll
        for (int ks = 0; ks < 8; ++ks) {
            const int k = ks * 32 + kb * 8;
            U4BF a0, a1;
            {
                float4 p = *(const float4*)(a0p + k);
                float4 q = *(const float4*)(a0p + k + 4);
                a0.u.x = pk2(p.x, p.y); a0.u.y = pk2(p.z, p.w);
                a0.u.z = pk2(q.x, q.y); a0.u.w = pk2(q.z, q.w);
            }
            {
                float4 p = *(const float4*)(a1p + k);
                float4 q = *(const float4*)(a1p + k + 4);
                a1.u.x = pk2(p.x, p.y); a1.u.y = pk2(p.z, p.w);
                a1.u.z = pk2(q.x, q.y); a1.u.w = pk2(q.z, q.w);
            }
            U4BF b[8];
#pragma unroll
            for (int fn = 0; fn < 8; ++fn)
                b[fn].u = bsh[(ks * 8 + fn) * 64 + lane];
#pragma unroll
            for (int fn = 0; fn < 8; ++fn) {
                acc[0][fn] = __builtin_amdgcn_mfma_f32_16x16x32_bf16(
                    a0.v, b[fn].v, acc[0][fn], 0, 0, 0);
                acc[1][fn] = __builtin_amdgcn_mfma_f32_16x16x32_bf16(
                    a1.v, b[fn].v, acc[1][fn], 0, 0, 0);
            }
        }

#pragma unroll
        for (int fm = 0; fm < 2; ++fm) {
#pragma unroll
            for (int r = 0; r < 4; ++r) {
                int grow = brow + wid * 32 + fm * 16 + (lane >> 4) * 4 + r;
                if (grow < N_NODES) {
                    unsigned short* dst = h + (size_t)grow * OUT_F + ln;
#pragma unroll
                    for (int fn = 0; fn < 8; ++fn)
                        dst[fn * 16] = f2bf(acc[fm][fn][r]);
                }
            }
        }
    } else {
        // ================= Pass C path: LDS counting-sort ==================
        int2*           skv   = (int2*)(smem);                       // 28,576 B
        unsigned short* sbin  = (unsigned short*)(smem + 28576);     //  7,144 B
        int*            cur   = (int*)(smem + 35720);                //  3,128 B
        int*            sdel  = (int*)(smem + 38848);                //  3,128 B
        int*            sscan = (int*)(smem + 41976);                //  1,024 B

        const int b = blockIdx.x - GEMM_BLOCKS;

        int c[BPTC];
        int ps = 0;
#pragma unroll
        for (int i = 0; i < BPTC; ++i) {
            int bin = t * BPTC + i;
            c[i] = (bin < NBIN) ? cntmat[(size_t)b * NBIN + bin] : 0;
            ps += c[i];
        }
        sscan[t] = ps;
        __syncthreads();
        for (int off = 1; off < 256; off <<= 1) {
            int add = (t >= off) ? sscan[t - off] : 0;
            __syncthreads();
            sscan[t] += add;
            __syncthreads();
        }
        int excl = sscan[t] - ps;
#pragma unroll
        for (int i = 0; i < BPTC; ++i) {
            int bin = t * BPTC + i;
            if (bin < NBIN) {
                cur[bin]  = excl;
                sdel[bin] = bucket_base[bin] + blockbase[(size_t)b * NBIN + bin] - excl;
                excl += c[i];
            }
        }
        __syncthreads();

        const int base = b * CHUNK;
        const int end  = min(base + CHUNK, N_EDGES);
        for (int i = base + t * 4; i < end; i += 1024) {
            int4   r = *(const int4*)(erow + i);
            int4   cc = *(const int4*)(ecol + i);
            float4 v = *(const float4*)(eval_ + i);
            int bin, pos;
            bin = r.x >> 7; pos = atomicAdd(&cur[bin], 1);
            skv[pos] = make_int2(cc.x | ((r.x & 127) << 17), __float_as_int(v.x));
            sbin[pos] = (unsigned short)bin;
            bin = r.y >> 7; pos = atomicAdd(&cur[bin], 1);
            skv[pos] = make_int2(cc.y | ((r.y & 127) << 17), __float_as_int(v.y));
            sbin[pos] = (unsigned short)bin;
            bin = r.z >> 7; pos = atomicAdd(&cur[bin], 1);
            skv[pos] = make_int2(cc.z | ((r.z & 127) << 17), __float_as_int(v.z));
            sbin[pos] = (unsigned short)bin;
            bin = r.w >> 7; pos = atomicAdd(&cur[bin], 1);
            skv[pos] = make_int2(cc.w | ((r.w & 127) << 17), __float_as_int(v.w));
            sbin[pos] = (unsigned short)bin;
        }
        __syncthreads();

        const int n = end - base;
        for (int i = t; i < n; i += 256) {
            int2 kv = skv[i];
            tmp[sdel[sbin[i]] + i] = kv;
        }
    }
}

// ---------- fused D+aggregate v2: single tmp read, index-permutation sort ------
__global__ __launch_bounds__(512) void fused_da_kernel(
    const int2* __restrict__ tmp, const int* __restrict__ bucket_base,
    const unsigned* __restrict__ h2, const float* __restrict__ bias,
    float* __restrict__ out)
{
    __shared__ int2 skv[CAP];               // 36,864 B unsorted edges
    __shared__ unsigned short sidx[CAP];    //  9,216 B sorted -> unsorted index
    __shared__ int  srow[RPB];
    __shared__ int  scnt[RPB];
    __shared__ int  cursor[RPB];            // total ~47.6 KB -> 3 blocks/CU

    const int t    = threadIdx.x;
    const int lane = t & 63;
    const int w    = t >> 6;       // wave 0..7
    const int j    = blockIdx.x;
    const int base = bucket_base[j];
    int n = bucket_base[j + 1] - base;
    if (n > CAP) n = CAP;          // safety (statistically unreachable)

    // single global read: stage edges + fine histogram in one pass
    if (t < RPB) cursor[t] = 0;
    __syncthreads();
    for (int i = t; i < n; i += 512) {
        int2 p = tmp[base + i];
        skv[i] = p;
        atomicAdd(&cursor[p.x >> 17], 1);
    }
    __syncthreads();

    // exclusive scan of 128 bins
    if (t < RPB) { scnt[t] = cursor[t]; srow[t] = cursor[t]; }
    __syncthreads();
    for (int off = 1; off < RPB; off <<= 1) {
        int add = (t >= off && t < RPB) ? srow[t - off] : 0;
        __syncthreads();
        if (t < RPB) srow[t] += add;
        __syncthreads();
    }
    if (t < RPB) { int ex = srow[t] - scnt[t]; srow[t] = ex; cursor[t] = ex; }
    __syncthreads();

    // build permutation: sidx[sorted_pos] = unsorted LDS index
    for (int i = t; i < n; i += 512) {
        int rl = skv[i].x >> 17;
        int pos = atomicAdd(&cursor[rl], 1);
        sidx[pos] = (unsigned short)i;
    }
    __syncthreads();

    // aggregate: wave w handles rows w*16 .. w*16+15; lane owns feats {2l, 2l+1}
    const unsigned* hb = h2 + lane;
#pragma unroll 1
    for (int rr = w * 16; rr < w * 16 + 16; ++rr) {
        int gr = j * RPB + rr;
        if (gr >= N_NODES) break;               // wave-uniform
        int s = srow[rr];
        int end = s + scnt[rr];
        float ax = 0.f, ay = 0.f;

        int e = s;
        for (; e + 7 < end; e += 8) {
            int2 p0 = skv[sidx[e]];
            int2 p1 = skv[sidx[e + 1]];
            int2 p2 = skv[sidx[e + 2]];
            int2 p3 = skv[sidx[e + 3]];
            int2 p4 = skv[sidx[e + 4]];
            int2 p5 = skv[sidx[e + 5]];
            int2 p6 = skv[sidx[e + 6]];
            int2 p7 = skv[sidx[e + 7]];
            unsigned u0 = hb[(size_t)(p0.x & 0x1FFFF) << 6];
            unsigned u1 = hb[(size_t)(p1.x & 0x1FFFF) << 6];
            unsigned u2 = hb[(size_t)(p2.x & 0x1FFFF) << 6];
            unsigned u3 = hb[(size_t)(p3.x & 0x1FFFF) << 6];
            unsigned u4 = hb[(size_t)(p4.x & 0x1FFFF) << 6];
            unsigned u5 = hb[(size_t)(p5.x & 0x1FFFF) << 6];
            unsigned u6 = hb[(size_t)(p6.x & 0x1FFFF) << 6];
            unsigned u7 = hb[(size_t)(p7.x & 0x1FFFF) << 6];
            float v0 = __int_as_float(p0.y), v1 = __int_as_float(p1.y);
            float v2 = __int_as_float(p2.y), v3 = __int_as_float(p3.y);
            float v4 = __int_as_float(p4.y), v5 = __int_as_float(p5.y);
            float v6 = __int_as_float(p6.y), v7 = __int_as_float(p7.y);
            ax = fmaf(v0, __uint_as_float(u0 << 16), ax);
            ay = fmaf(v0, __uint_as_float(u0 & 0xFFFF0000u), ay);
            ax = fmaf(v1, __uint_as_float(u1 << 16), ax);
            ay = fmaf(v1, __uint_as_float(u1 & 0xFFFF0000u), ay);
            ax = fmaf(v2, __uint_as_float(u2 << 16), ax);
            ay = fmaf(v2, __uint_as_float(u2 & 0xFFFF0000u), ay);
            ax = fmaf(v3, __uint_as_float(u3 << 16), ax);
            ay = fmaf(v3, __uint_as_float(u3 & 0xFFFF0000u), ay);
            ax = fmaf(v4, __uint_as_float(u4 << 16), ax);
            ay = fmaf(v4, __uint_as_float(u4 & 0xFFFF0000u), ay);
            ax = fmaf(v5, __uint_as_float(u5 << 16), ax);
            ay = fmaf(v5, __uint_as_float(u5 & 0xFFFF0000u), ay);
            ax = fmaf(v6, __uint_as_float(u6 << 16), ax);
            ay = fmaf(v6, __uint_as_float(u6 & 0xFFFF0000u), ay);
            ax = fmaf(v7, __uint_as_float(u7 << 16), ax);
            ay = fmaf(v7, __uint_as_float(u7 & 0xFFFF0000u), ay);
        }
        for (; e < end; ++e) {
            int2 p0 = skv[sidx[e]];
            unsigned u0 = hb[(size_t)(p0.x & 0x1FFFF) << 6];
            float v0 = __int_as_float(p0.y);
            ax = fmaf(v0, __uint_as_float(u0 << 16), ax);
            ay = fmaf(v0, __uint_as_float(u0 & 0xFFFF0000u), ay);
        }

        float2 bb = *(const float2*)(bias + lane * 2);
        *(float2*)(out + (size_t)gr * OUT_F + lane * 2) =
            make_float2(ax + bb.x, ay + bb.y);
    }
}

// -------------------- launch --------------------
extern "C" void kernel_launch(void* const* d_in, const int* in_sizes, int n_in,
                              void* d_out, int out_size, void* d_ws, size_t ws_size,
                              hipStream_t stream)
{
    const float* x     = (const float*)d_in[0];
    const int*   erow  = (const int*)d_in[1];
    const int*   ecol  = (const int*)d_in[2];
    const float* eval_ = (const float*)d_in[3];
    const float* w     = (const float*)d_in[4];
    const float* bias  = (const float*)d_in[5];
    float*       out   = (float*)d_out;

    // workspace layout (bytes):
    //   h (bf16):    0          .. 25,600,000
    //   tmp:         25,600,000 .. 51,200,000
    //   cntmat:      51,200,000 .. 54,002,688   (896 x 782 int)
    //   blockbase:   54,002,688 .. 56,805,376
    //   tot:         56,805,376 .. 56,808,504 -> pad 56,812,000
    //   bucket_base: 56,812,000 .. 56,815,132 -> pad 56,816,000 (783 int)
    //   wbfF:        56,816,000 .. 56,881,536   (~56.9 MB)
    char* ws = (char*)d_ws;
    unsigned short* h           = (unsigned short*)(ws);
    int2*           tmp         = (int2*)(ws + 25600000);
    int*            cntmat      = (int*)(ws + 51200000);
    int*            blockbase   = (int*)(ws + 54002688);
    int*            tot         = (int*)(ws + 56805376);
    int*            bucket_base = (int*)(ws + 56812000);
    uint4*          wbfF        = (uint4*)(ws + 56816000);

    // 1) w -> frag-ordered bf16  ||  coarse histogram (both input-only)
    hipLaunchKernelGGL(conv_hist_kernel, dim3(CONV_BLOCKS + NBC), dim3(256), 0, stream,
                       w, wbfF, erow, cntmat);

    // 2) scans
    hipLaunchKernelGGL(pass_b_kernel, dim3(NBIN), dim3(256), 0, stream,
                       cntmat, blockbase, tot);
    hipLaunchKernelGGL(pass_b2_kernel, dim3(1), dim3(512), 0, stream, tot, bucket_base);

    // 3) GEMM (needs wbfF)  ||  counting-sort scatter (needs scans) — independent
    hipLaunchKernelGGL(gemm_passc_kernel, dim3(GEMM_BLOCKS + NBC), dim3(256), 0, stream,
                       x, wbfF, h, erow, ecol, eval_, cntmat, blockbase,
                       bucket_base, tmp);

    // 4) fused fine-sort + aggregate + bias (needs h and tmp)
    hipLaunchKernelGGL(fused_da_kernel, dim3(NBIN), dim3(512), 0, stream,
                       tmp, bucket_base, (const unsigned*)h, bias, out);
}

// Round 14
// 191.596 us; speedup vs baseline: 1.2337x; 1.2337x over previous
//
#include <hip/hip_runtime.h>
#include <hip/hip_bf16.h>

#define N_NODES 100000
#define N_EDGES 3200000
#define IN_F 256
#define OUT_F 128

#define RPB 128           // rows per bucket
#define NBIN 782          // ceil(100000/128); bin = row >> 7
#define NBC  896          // sort-chunk blocks
#define CHUNK 3572        // edges per chunk (896*3572 >= 3.2M, %4==0)
#define GEMM_BLOCKS 782   // (N_NODES + 127) / 128
#define CONV_BLOCKS 16
#define BPTC 4            // bins per thread in pass C local scan
#define CAP 4608          // LDS edge capacity per bucket (mean 4096, sigma ~64)

typedef __attribute__((ext_vector_type(8))) short bf16x8;
typedef __attribute__((ext_vector_type(4))) float f32x4;

union U4BF { uint4 u; bf16x8 v; };

__device__ inline unsigned short f2bf(float f) {
    return __bfloat16_as_ushort(__float2bfloat16(f));
}
__device__ inline unsigned pk2(float a, float b) {
    unsigned la = __bfloat16_as_ushort(__float2bfloat16(a));
    unsigned lb = __bfloat16_as_ushort(__float2bfloat16(b));
    return la | (lb << 16);
}

// ---------- Kernel 1: fused w-conversion (blocks 0..15) + coarse hist ----------
__global__ __launch_bounds__(256) void conv_hist_kernel(
    const float* __restrict__ w, uint4* __restrict__ wbfF,
    const int* __restrict__ erow, int* __restrict__ cntmat)
{
    __shared__ int lhist[NBIN];
    const int t = threadIdx.x;

    if (blockIdx.x < CONV_BLOCKS) {
        int tid = blockIdx.x * 256 + t;   // 0..4095
        int ks = tid >> 9;
        int fn = (tid >> 6) & 7;
        int l  = tid & 63;
        int c  = fn * 16 + (l & 15);
        int k0 = ks * 32 + (l >> 4) * 8;
        const float* wp = w + (size_t)k0 * OUT_F + c;
        uint4 u;
        u.x = pk2(wp[0 * OUT_F], wp[1 * OUT_F]);
        u.y = pk2(wp[2 * OUT_F], wp[3 * OUT_F]);
        u.z = pk2(wp[4 * OUT_F], wp[5 * OUT_F]);
        u.w = pk2(wp[6 * OUT_F], wp[7 * OUT_F]);
        wbfF[tid] = u;
    } else {
        const int b = blockIdx.x - CONV_BLOCKS;
        for (int i = t; i < NBIN; i += 256) lhist[i] = 0;
        __syncthreads();

        const int base = b * CHUNK;
        const int end  = min(base + CHUNK, N_EDGES);
        for (int i = base + t * 4; i < end; i += 1024) {
            int4 r = *(const int4*)(erow + i);
            atomicAdd(&lhist[r.x >> 7], 1);
            atomicAdd(&lhist[r.y >> 7], 1);
            atomicAdd(&lhist[r.z >> 7], 1);
            atomicAdd(&lhist[r.w >> 7], 1);
        }
        __syncthreads();

        int* dst = cntmat + (size_t)b * NBIN;
        for (int j = t; j < NBIN; j += 256) dst[j] = lhist[j];
    }
}

// ---------- Pass B: per-bin exclusive scan over 896 chunk-blocks ----------
__global__ __launch_bounds__(256) void pass_b_kernel(
    const int* __restrict__ cntmat, int* __restrict__ blockbase,
    int* __restrict__ tot)
{
    __shared__ int sh[256];
    const int t = threadIdx.x;
    const int j = blockIdx.x;
    int c[4];
    int ps = 0;
#pragma unroll
    for (int i = 0; i < 4; ++i) {
        int bb = 4 * t + i;
        c[i] = (bb < NBC) ? cntmat[(size_t)bb * NBIN + j] : 0;
        ps += c[i];
    }
    sh[t] = ps;
    __syncthreads();
    for (int off = 1; off < 256; off <<= 1) {
        int add = (t >= off) ? sh[t - off] : 0;
        __syncthreads();
        sh[t] += add;
        __syncthreads();
    }
    int excl = sh[t] - ps;
#pragma unroll
    for (int i = 0; i < 4; ++i) {
        int bb = 4 * t + i;
        if (bb < NBC) { blockbase[(size_t)bb * NBIN + j] = excl; excl += c[i]; }
    }
    if (t == 255) tot[j] = sh[255];
}

// ---------- Pass B2: exclusive scan of 782 bucket totals ----------
__global__ __launch_bounds__(512) void pass_b2_kernel(
    const int* __restrict__ tot, int* __restrict__ bucket_base)
{
    __shared__ int sh[512];
    const int t = threadIdx.x;
    const int i0 = 2 * t, i1 = 2 * t + 1;
    int v0 = (i0 < NBIN) ? tot[i0] : 0;
    int v1 = (i1 < NBIN) ? tot[i1] : 0;
    int ps = v0 + v1;
    sh[t] = ps;
    __syncthreads();
    for (int off = 1; off < 512; off <<= 1) {
        int add = (t >= off) ? sh[t - off] : 0;
        __syncthreads();
        sh[t] += add;
        __syncthreads();
    }
    int excl = sh[t] - ps;
    if (i0 <= NBIN) bucket_base[i0] = excl;
    if (i1 <= NBIN) bucket_base[i1] = excl + v0;     // i1==NBIN -> N_EDGES
}

// ---------- Kernel 4: fused GEMM (blocks 0..781) + pass C (782..1677) ----------
__global__ __launch_bounds__(256) void gemm_passc_kernel(
    const float* __restrict__ x, const uint4* __restrict__ wbfF,
    unsigned short* __restrict__ h,
    const int* __restrict__ erow, const int* __restrict__ ecol,
    const float* __restrict__ eval_, const int* __restrict__ cntmat,
    const int* __restrict__ blockbase, const int* __restrict__ bucket_base,
    int2* __restrict__ tmp)
{
    __shared__ __align__(16) char smem[65536];
    const int t = threadIdx.x;

    if (blockIdx.x < GEMM_BLOCKS) {
        // ================= GEMM path =================
        uint4* bsh = (uint4*)smem;
        const int lane = t & 63;
        const int wid  = t >> 6;
        const int brow = blockIdx.x * 128;
        const int ln   = lane & 15;
        const int kb   = lane >> 4;

#pragma unroll
        for (int i = 0; i < 16; ++i) bsh[i * 256 + t] = wbfF[i * 256 + t];

        int r0 = brow + wid * 32 + ln;
        int r1 = r0 + 16;
        const float* a0p = x + (size_t)(r0 < N_NODES ? r0 : N_NODES - 1) * IN_F;
        const float* a1p = x + (size_t)(r1 < N_NODES ? r1 : N_NODES - 1) * IN_F;

        f32x4 acc[2][8] = {};
        __syncthreads();

#pragma unroll
        for (int ks = 0; ks < 8; ++ks) {
            const int k = ks * 32 + kb * 8;
            U4BF a0, a1;
            {
                float4 p = *(const float4*)(a0p + k);
                float4 q = *(const float4*)(a0p + k + 4);
                a0.u.x = pk2(p.x, p.y); a0.u.y = pk2(p.z, p.w);
                a0.u.z = pk2(q.x, q.y); a0.u.w = pk2(q.z, q.w);
            }
            {
                float4 p = *(const float4*)(a1p + k);
                float4 q = *(const float4*)(a1p + k + 4);
                a1.u.x = pk2(p.x, p.y); a1.u.y = pk2(p.z, p.w);
                a1.u.z = pk2(q.x, q.y); a1.u.w = pk2(q.z, q.w);
            }
            U4BF b[8];
#pragma unroll
            for (int fn = 0; fn < 8; ++fn)
                b[fn].u = bsh[(ks * 8 + fn) * 64 + lane];
#pragma unroll
            for (int fn = 0; fn < 8; ++fn) {
                acc[0][fn] = __builtin_amdgcn_mfma_f32_16x16x32_bf16(
                    a0.v, b[fn].v, acc[0][fn], 0, 0, 0);
                acc[1][fn] = __builtin_amdgcn_mfma_f32_16x16x32_bf16(
                    a1.v, b[fn].v, acc[1][fn], 0, 0, 0);
            }
        }

#pragma unroll
        for (int fm = 0; fm < 2; ++fm) {
#pragma unroll
            for (int r = 0; r < 4; ++r) {
                int grow = brow + wid * 32 + fm * 16 + (lane >> 4) * 4 + r;
                if (grow < N_NODES) {
                    unsigned short* dst = h + (size_t)grow * OUT_F + ln;
#pragma unroll
                    for (int fn = 0; fn < 8; ++fn)
                        dst[fn * 16] = f2bf(acc[fm][fn][r]);
                }
            }
        }
    } else {
        // ================= Pass C path: LDS counting-sort ==================
        int2*           skv   = (int2*)(smem);                       // 28,576 B
        unsigned short* sbin  = (unsigned short*)(smem + 28576);     //  7,144 B
        int*            cur   = (int*)(smem + 35720);                //  3,128 B
        int*            sdel  = (int*)(smem + 38848);                //  3,128 B
        int*            sscan = (int*)(smem + 41976);                //  1,024 B

        const int b = blockIdx.x - GEMM_BLOCKS;

        int c[BPTC];
        int ps = 0;
#pragma unroll
        for (int i = 0; i < BPTC; ++i) {
            int bin = t * BPTC + i;
            c[i] = (bin < NBIN) ? cntmat[(size_t)b * NBIN + bin] : 0;
            ps += c[i];
        }
        sscan[t] = ps;
        __syncthreads();
        for (int off = 1; off < 256; off <<= 1) {
            int add = (t >= off) ? sscan[t - off] : 0;
            __syncthreads();
            sscan[t] += add;
            __syncthreads();
        }
        int excl = sscan[t] - ps;
#pragma unroll
        for (int i = 0; i < BPTC; ++i) {
            int bin = t * BPTC + i;
            if (bin < NBIN) {
                cur[bin]  = excl;
                sdel[bin] = bucket_base[bin] + blockbase[(size_t)b * NBIN + bin] - excl;
                excl += c[i];
            }
        }
        __syncthreads();

        const int base = b * CHUNK;
        const int end  = min(base + CHUNK, N_EDGES);
        for (int i = base + t * 4; i < end; i += 1024) {
            int4   r = *(const int4*)(erow + i);
            int4   cc = *(const int4*)(ecol + i);
            float4 v = *(const float4*)(eval_ + i);
            int bin, pos;
            bin = r.x >> 7; pos = atomicAdd(&cur[bin], 1);
            skv[pos] = make_int2(cc.x | ((r.x & 127) << 17), __float_as_int(v.x));
            sbin[pos] = (unsigned short)bin;
            bin = r.y >> 7; pos = atomicAdd(&cur[bin], 1);
            skv[pos] = make_int2(cc.y | ((r.y & 127) << 17), __float_as_int(v.y));
            sbin[pos] = (unsigned short)bin;
            bin = r.z >> 7; pos = atomicAdd(&cur[bin], 1);
            skv[pos] = make_int2(cc.z | ((r.z & 127) << 17), __float_as_int(v.z));
            sbin[pos] = (unsigned short)bin;
            bin = r.w >> 7; pos = atomicAdd(&cur[bin], 1);
            skv[pos] = make_int2(cc.w | ((r.w & 127) << 17), __float_as_int(v.w));
            sbin[pos] = (unsigned short)bin;
        }
        __syncthreads();

        const int n = end - base;
        for (int i = t; i < n; i += 256) {
            int2 kv = skv[i];
            tmp[sdel[sbin[i]] + i] = kv;
        }
    }
}

// ---------- fused D+aggregate (r12-proven): physical LDS sort + reg gather -----
__global__ __launch_bounds__(512) void fused_da_kernel(
    const int2* __restrict__ tmp, const int* __restrict__ bucket_base,
    const unsigned* __restrict__ h2, const float* __restrict__ bias,
    float* __restrict__ out)
{
    __shared__ int2 skv[CAP];      // 36,864 B sorted edges (col, val)
    __shared__ int  srow[RPB];
    __shared__ int  scnt[RPB];
    __shared__ int  cursor[RPB];   // total 38,400 B -> 4 blocks/CU

    const int t    = threadIdx.x;
    const int lane = t & 63;
    const int w    = t >> 6;       // wave 0..7
    const int j    = blockIdx.x;
    const int base = bucket_base[j];
    int n = bucket_base[j + 1] - base;
    if (n > CAP) n = CAP;          // safety (statistically unreachable)

    // fine histogram (128 bins)
    if (t < RPB) cursor[t] = 0;
    __syncthreads();
    for (int i = t; i < n; i += 512)
        atomicAdd(&cursor[tmp[base + i].x >> 17], 1);
    __syncthreads();
    if (t < RPB) { scnt[t] = cursor[t]; srow[t] = cursor[t]; }
    __syncthreads();
    for (int off = 1; off < RPB; off <<= 1) {
        int add = (t >= off && t < RPB) ? srow[t - off] : 0;
        __syncthreads();
        if (t < RPB) srow[t] += add;
        __syncthreads();
    }
    if (t < RPB) { int ex = srow[t] - scnt[t]; srow[t] = ex; cursor[t] = ex; }
    __syncthreads();

    // scatter into LDS sorted by fine row (tmp L2-hot re-read)
    for (int i = t; i < n; i += 512) {
        int2 p = tmp[base + i];
        int rl = p.x >> 17;
        int pos = atomicAdd(&cursor[rl], 1);
        skv[pos] = make_int2(p.x & 0x1FFFF, p.y);
    }
    __syncthreads();

    // aggregate: wave w handles rows w*16 .. w*16+15; lane owns feats {2l, 2l+1}
    const unsigned* hb = h2 + lane;
#pragma unroll 1
    for (int rr = w * 16; rr < w * 16 + 16; ++rr) {
        int gr = j * RPB + rr;
        if (gr >= N_NODES) break;               // wave-uniform
        int s = srow[rr];
        int end = s + scnt[rr];
        float ax = 0.f, ay = 0.f;

        int e = s;
        for (; e + 7 < end; e += 8) {
            int2 p0 = skv[e];
            int2 p1 = skv[e + 1];
            int2 p2 = skv[e + 2];
            int2 p3 = skv[e + 3];
            int2 p4 = skv[e + 4];
            int2 p5 = skv[e + 5];
            int2 p6 = skv[e + 6];
            int2 p7 = skv[e + 7];
            unsigned u0 = hb[(size_t)p0.x << 6];
            unsigned u1 = hb[(size_t)p1.x << 6];
            unsigned u2 = hb[(size_t)p2.x << 6];
            unsigned u3 = hb[(size_t)p3.x << 6];
            unsigned u4 = hb[(size_t)p4.x << 6];
            unsigned u5 = hb[(size_t)p5.x << 6];
            unsigned u6 = hb[(size_t)p6.x << 6];
            unsigned u7 = hb[(size_t)p7.x << 6];
            float v0 = __int_as_float(p0.y), v1 = __int_as_float(p1.y);
            float v2 = __int_as_float(p2.y), v3 = __int_as_float(p3.y);
            float v4 = __int_as_float(p4.y), v5 = __int_as_float(p5.y);
            float v6 = __int_as_float(p6.y), v7 = __int_as_float(p7.y);
            ax = fmaf(v0, __uint_as_float(u0 << 16), ax);
            ay = fmaf(v0, __uint_as_float(u0 & 0xFFFF0000u), ay);
            ax = fmaf(v1, __uint_as_float(u1 << 16), ax);
            ay = fmaf(v1, __uint_as_float(u1 & 0xFFFF0000u), ay);
            ax = fmaf(v2, __uint_as_float(u2 << 16), ax);
            ay = fmaf(v2, __uint_as_float(u2 & 0xFFFF0000u), ay);
            ax = fmaf(v3, __uint_as_float(u3 << 16), ax);
            ay = fmaf(v3, __uint_as_float(u3 & 0xFFFF0000u), ay);
            ax = fmaf(v4, __uint_as_float(u4 << 16), ax);
            ay = fmaf(v4, __uint_as_float(u4 & 0xFFFF0000u), ay);
            ax = fmaf(v5, __uint_as_float(u5 << 16), ax);
            ay = fmaf(v5, __uint_as_float(u5 & 0xFFFF0000u), ay);
            ax = fmaf(v6, __uint_as_float(u6 << 16), ax);
            ay = fmaf(v6, __uint_as_float(u6 & 0xFFFF0000u), ay);
            ax = fmaf(v7, __uint_as_float(u7 << 16), ax);
            ay = fmaf(v7, __uint_as_float(u7 & 0xFFFF0000u), ay);
        }
        for (; e < end; ++e) {
            int2 p0 = skv[e];
            unsigned u0 = hb[(size_t)p0.x << 6];
            float v0 = __int_as_float(p0.y);
            ax = fmaf(v0, __uint_as_float(u0 << 16), ax);
            ay = fmaf(v0, __uint_as_float(u0 & 0xFFFF0000u), ay);
        }

        float2 bb = *(const float2*)(bias + lane * 2);
        *(float2*)(out + (size_t)gr * OUT_F + lane * 2) =
            make_float2(ax + bb.x, ay + bb.y);
    }
}

// -------------------- launch --------------------
extern "C" void kernel_launch(void* const* d_in, const int* in_sizes, int n_in,
                              void* d_out, int out_size, void* d_ws, size_t ws_size,
                              hipStream_t stream)
{
    const float* x     = (const float*)d_in[0];
    const int*   erow  = (const int*)d_in[1];
    const int*   ecol  = (const int*)d_in[2];
    const float* eval_ = (const float*)d_in[3];
    const float* w     = (const float*)d_in[4];
    const float* bias  = (const float*)d_in[5];
    float*       out   = (float*)d_out;

    // workspace layout (bytes):
    //   h (bf16):    0          .. 25,600,000
    //   tmp:         25,600,000 .. 51,200,000
    //   cntmat:      51,200,000 .. 54,002,688   (896 x 782 int)
    //   blockbase:   54,002,688 .. 56,805,376
    //   tot:         56,805,376 .. 56,808,504 -> pad 56,812,000
    //   bucket_base: 56,812,000 .. 56,815,132 -> pad 56,816,000 (783 int)
    //   wbfF:        56,816,000 .. 56,881,536   (~56.9 MB)
    char* ws = (char*)d_ws;
    unsigned short* h           = (unsigned short*)(ws);
    int2*           tmp         = (int2*)(ws + 25600000);
    int*            cntmat      = (int*)(ws + 51200000);
    int*            blockbase   = (int*)(ws + 54002688);
    int*            tot         = (int*)(ws + 56805376);
    int*            bucket_base = (int*)(ws + 56812000);
    uint4*          wbfF        = (uint4*)(ws + 56816000);

    // 1) w -> frag-ordered bf16  ||  coarse histogram (both input-only)
    hipLaunchKernelGGL(conv_hist_kernel, dim3(CONV_BLOCKS + NBC), dim3(256), 0, stream,
                       w, wbfF, erow, cntmat);

    // 2) scans
    hipLaunchKernelGGL(pass_b_kernel, dim3(NBIN), dim3(256), 0, stream,
                       cntmat, blockbase, tot);
    hipLaunchKernelGGL(pass_b2_kernel, dim3(1), dim3(512), 0, stream, tot, bucket_base);

    // 3) GEMM (needs wbfF)  ||  counting-sort scatter (needs scans) — independent
    hipLaunchKernelGGL(gemm_passc_kernel, dim3(GEMM_BLOCKS + NBC), dim3(256), 0, stream,
                       x, wbfF, h, erow, ecol, eval_, cntmat, blockbase,
                       bucket_base, tmp);

    // 4) fused fine-sort + aggregate + bias (needs h and tmp)
    hipLaunchKernelGGL(fused_da_kernel, dim3(NBIN), dim3(512), 0, stream,
                       tmp, bucket_base, (const unsigned*)h, bias, out);
}

// Round 15
// 185.265 us; speedup vs baseline: 1.2759x; 1.0342x over previous
//
#include <hip/hip_runtime.h>
#include <hip/hip_bf16.h>

#define N_NODES 100000
#define N_EDGES 3200000
#define IN_F 256
#define OUT_F 128

#define RPB 100           // rows per bucket (1000 * 100 = exactly N_NODES)
#define NBIN 1000         // bin = row / 100
#define NBC  896          // sort-chunk blocks
#define CHUNK 3572        // edges per chunk (896*3572 >= 3.2M, %4==0)
#define GEMM_BLOCKS 782   // (N_NODES + 127) / 128
#define CONV_BLOCKS 16
#define BPTC 4            // bins per thread in pass C local scan (4*256 >= 1000)
#define CAP 3712          // LDS edge capacity per bucket (mean 3200, sigma ~56)

typedef __attribute__((ext_vector_type(8))) short bf16x8;
typedef __attribute__((ext_vector_type(4))) float f32x4;

union U4BF { uint4 u; bf16x8 v; };

__device__ inline unsigned short f2bf(float f) {
    return __bfloat16_as_ushort(__float2bfloat16(f));
}
__device__ inline unsigned pk2(float a, float b) {
    unsigned la = __bfloat16_as_ushort(__float2bfloat16(a));
    unsigned lb = __bfloat16_as_ushort(__float2bfloat16(b));
    return la | (lb << 16);
}

// ---------- Kernel 1: fused w-conversion (blocks 0..15) + coarse hist ----------
__global__ __launch_bounds__(256) void conv_hist_kernel(
    const float* __restrict__ w, uint4* __restrict__ wbfF,
    const int* __restrict__ erow, int* __restrict__ cntmat)
{
    __shared__ int lhist[NBIN];
    const int t = threadIdx.x;

    if (blockIdx.x < CONV_BLOCKS) {
        int tid = blockIdx.x * 256 + t;   // 0..4095
        int ks = tid >> 9;
        int fn = (tid >> 6) & 7;
        int l  = tid & 63;
        int c  = fn * 16 + (l & 15);
        int k0 = ks * 32 + (l >> 4) * 8;
        const float* wp = w + (size_t)k0 * OUT_F + c;
        uint4 u;
        u.x = pk2(wp[0 * OUT_F], wp[1 * OUT_F]);
        u.y = pk2(wp[2 * OUT_F], wp[3 * OUT_F]);
        u.z = pk2(wp[4 * OUT_F], wp[5 * OUT_F]);
        u.w = pk2(wp[6 * OUT_F], wp[7 * OUT_F]);
        wbfF[tid] = u;
    } else {
        const int b = blockIdx.x - CONV_BLOCKS;
        for (int i = t; i < NBIN; i += 256) lhist[i] = 0;
        __syncthreads();

        const int base = b * CHUNK;
        const int end  = min(base + CHUNK, N_EDGES);
        for (int i = base + t * 4; i < end; i += 1024) {
            int4 r = *(const int4*)(erow + i);
            atomicAdd(&lhist[(unsigned)r.x / 100u], 1);
            atomicAdd(&lhist[(unsigned)r.y / 100u], 1);
            atomicAdd(&lhist[(unsigned)r.z / 100u], 1);
            atomicAdd(&lhist[(unsigned)r.w / 100u], 1);
        }
        __syncthreads();

        int* dst = cntmat + (size_t)b * NBIN;
        for (int j = t; j < NBIN; j += 256) dst[j] = lhist[j];
    }
}

// ---------- Pass B: per-bin exclusive scan over 896 chunk-blocks ----------
__global__ __launch_bounds__(256) void pass_b_kernel(
    const int* __restrict__ cntmat, int* __restrict__ blockbase,
    int* __restrict__ tot)
{
    __shared__ int sh[256];
    const int t = threadIdx.x;
    const int j = blockIdx.x;
    int c[4];
    int ps = 0;
#pragma unroll
    for (int i = 0; i < 4; ++i) {
        int bb = 4 * t + i;
        c[i] = (bb < NBC) ? cntmat[(size_t)bb * NBIN + j] : 0;
        ps += c[i];
    }
    sh[t] = ps;
    __syncthreads();
    for (int off = 1; off < 256; off <<= 1) {
        int add = (t >= off) ? sh[t - off] : 0;
        __syncthreads();
        sh[t] += add;
        __syncthreads();
    }
    int excl = sh[t] - ps;
#pragma unroll
    for (int i = 0; i < 4; ++i) {
        int bb = 4 * t + i;
        if (bb < NBC) { blockbase[(size_t)bb * NBIN + j] = excl; excl += c[i]; }
    }
    if (t == 255) tot[j] = sh[255];
}

// ---------- Pass B2: exclusive scan of 1000 bucket totals ----------
__global__ __launch_bounds__(512) void pass_b2_kernel(
    const int* __restrict__ tot, int* __restrict__ bucket_base)
{
    __shared__ int sh[512];
    const int t = threadIdx.x;
    const int i0 = 2 * t, i1 = 2 * t + 1;
    int v0 = (i0 < NBIN) ? tot[i0] : 0;
    int v1 = (i1 < NBIN) ? tot[i1] : 0;
    int ps = v0 + v1;
    sh[t] = ps;
    __syncthreads();
    for (int off = 1; off < 512; off <<= 1) {
        int add = (t >= off) ? sh[t - off] : 0;
        __syncthreads();
        sh[t] += add;
        __syncthreads();
    }
    int excl = sh[t] - ps;
    if (i0 <= NBIN) bucket_base[i0] = excl;
    if (i1 <= NBIN) bucket_base[i1] = excl + v0;     // i1==NBIN -> N_EDGES
}

// ---------- Kernel 4: fused GEMM (blocks 0..781) + pass C (782..1677) ----------
__global__ __launch_bounds__(256) void gemm_passc_kernel(
    const float* __restrict__ x, const uint4* __restrict__ wbfF,
    unsigned short* __restrict__ h,
    const int* __restrict__ erow, const int* __restrict__ ecol,
    const float* __restrict__ eval_, const int* __restrict__ cntmat,
    const int* __restrict__ blockbase, const int* __restrict__ bucket_base,
    int2* __restrict__ tmp)
{
    __shared__ __align__(16) char smem[65536];
    const int t = threadIdx.x;

    if (blockIdx.x < GEMM_BLOCKS) {
        // ================= GEMM path =================
        uint4* bsh = (uint4*)smem;
        const int lane = t & 63;
        const int wid  = t >> 6;
        const int brow = blockIdx.x * 128;
        const int ln   = lane & 15;
        const int kb   = lane >> 4;

#pragma unroll
        for (int i = 0; i < 16; ++i) bsh[i * 256 + t] = wbfF[i * 256 + t];

        int r0 = brow + wid * 32 + ln;
        int r1 = r0 + 16;
        const float* a0p = x + (size_t)(r0 < N_NODES ? r0 : N_NODES - 1) * IN_F;
        const float* a1p = x + (size_t)(r1 < N_NODES ? r1 : N_NODES - 1) * IN_F;

        f32x4 acc[2][8] = {};
        __syncthreads();

#pragma unroll
        for (int ks = 0; ks < 8; ++ks) {
            const int k = ks * 32 + kb * 8;
            U4BF a0, a1;
            {
                float4 p = *(const float4*)(a0p + k);
                float4 q = *(const float4*)(a0p + k + 4);
                a0.u.x = pk2(p.x, p.y); a0.u.y = pk2(p.z, p.w);
                a0.u.z = pk2(q.x, q.y); a0.u.w = pk2(q.z, q.w);
            }
            {
                float4 p = *(const float4*)(a1p + k);
                float4 q = *(const float4*)(a1p + k + 4);
                a1.u.x = pk2(p.x, p.y); a1.u.y = pk2(p.z, p.w);
                a1.u.z = pk2(q.x, q.y); a1.u.w = pk2(q.z, q.w);
            }
            U4BF b[8];
#pragma unroll
            for (int fn = 0; fn < 8; ++fn)
                b[fn].u = bsh[(ks * 8 + fn) * 64 + lane];
#pragma unroll
            for (int fn = 0; fn < 8; ++fn) {
                acc[0][fn] = __builtin_amdgcn_mfma_f32_16x16x32_bf16(
                    a0.v, b[fn].v, acc[0][fn], 0, 0, 0);
                acc[1][fn] = __builtin_amdgcn_mfma_f32_16x16x32_bf16(
                    a1.v, b[fn].v, acc[1][fn], 0, 0, 0);
            }
        }

#pragma unroll
        for (int fm = 0; fm < 2; ++fm) {
#pragma unroll
            for (int r = 0; r < 4; ++r) {
                int grow = brow + wid * 32 + fm * 16 + (lane >> 4) * 4 + r;
                if (grow < N_NODES) {
                    unsigned short* dst = h + (size_t)grow * OUT_F + ln;
#pragma unroll
                    for (int fn = 0; fn < 8; ++fn)
                        dst[fn * 16] = f2bf(acc[fm][fn][r]);
                }
            }
        }
    } else {
        // ================= Pass C path: LDS counting-sort ==================
        int2*           skv   = (int2*)(smem);                       // 28,576 B
        unsigned short* sbin  = (unsigned short*)(smem + 28576);     //  7,144 B
        int*            cur   = (int*)(smem + 35720);                //  4,000 B
        int*            sdel  = (int*)(smem + 39720);                //  4,000 B
        int*            sscan = (int*)(smem + 43720);                //  1,024 B

        const int b = blockIdx.x - GEMM_BLOCKS;

        int c[BPTC];
        int ps = 0;
#pragma unroll
        for (int i = 0; i < BPTC; ++i) {
            int bin = t * BPTC + i;
            c[i] = (bin < NBIN) ? cntmat[(size_t)b * NBIN + bin] : 0;
            ps += c[i];
        }
        sscan[t] = ps;
        __syncthreads();
        for (int off = 1; off < 256; off <<= 1) {
            int add = (t >= off) ? sscan[t - off] : 0;
            __syncthreads();
            sscan[t] += add;
            __syncthreads();
        }
        int excl = sscan[t] - ps;
#pragma unroll
        for (int i = 0; i < BPTC; ++i) {
            int bin = t * BPTC + i;
            if (bin < NBIN) {
                cur[bin]  = excl;
                sdel[bin] = bucket_base[bin] + blockbase[(size_t)b * NBIN + bin] - excl;
                excl += c[i];
            }
        }
        __syncthreads();

        const int base = b * CHUNK;
        const int end  = min(base + CHUNK, N_EDGES);
        for (int i = base + t * 4; i < end; i += 1024) {
            int4   r = *(const int4*)(erow + i);
            int4   cc = *(const int4*)(ecol + i);
            float4 v = *(const float4*)(eval_ + i);
            int bin, rl, pos;
            bin = (unsigned)r.x / 100u; rl = r.x - bin * 100;
            pos = atomicAdd(&cur[bin], 1);
            skv[pos] = make_int2(cc.x | (rl << 17), __float_as_int(v.x));
            sbin[pos] = (unsigned short)bin;
            bin = (unsigned)r.y / 100u; rl = r.y - bin * 100;
            pos = atomicAdd(&cur[bin], 1);
            skv[pos] = make_int2(cc.y | (rl << 17), __float_as_int(v.y));
            sbin[pos] = (unsigned short)bin;
            bin = (unsigned)r.z / 100u; rl = r.z - bin * 100;
            pos = atomicAdd(&cur[bin], 1);
            skv[pos] = make_int2(cc.z | (rl << 17), __float_as_int(v.z));
            sbin[pos] = (unsigned short)bin;
            bin = (unsigned)r.w / 100u; rl = r.w - bin * 100;
            pos = atomicAdd(&cur[bin], 1);
            skv[pos] = make_int2(cc.w | (rl << 17), __float_as_int(v.w));
            sbin[pos] = (unsigned short)bin;
        }
        __syncthreads();

        const int n = end - base;
        for (int i = t; i < n; i += 256) {
            int2 kv = skv[i];
            tmp[sdel[sbin[i]] + i] = kv;
        }
    }
}

// ---------- fused D+aggregate: physical LDS sort + reg gather, 100-row buckets -
__global__ __launch_bounds__(512) void fused_da_kernel(
    const int2* __restrict__ tmp, const int* __restrict__ bucket_base,
    const unsigned* __restrict__ h2, const float* __restrict__ bias,
    float* __restrict__ out)
{
    __shared__ int2 skv[CAP];      // 29,696 B sorted edges (col, val)
    __shared__ int  srow[RPB];
    __shared__ int  scnt[RPB];
    __shared__ int  cursor[RPB];   // total ~30.9 KB -> 5 blocks/CU capacity

    const int t    = threadIdx.x;
    const int lane = t & 63;
    const int w    = t >> 6;       // wave 0..7
    const int j    = blockIdx.x;
    const int base = bucket_base[j];
    int n = bucket_base[j + 1] - base;
    if (n > CAP) n = CAP;          // safety (statistically unreachable)

    // fine histogram (100 bins)
    if (t < RPB) cursor[t] = 0;
    __syncthreads();
    for (int i = t; i < n; i += 512)
        atomicAdd(&cursor[tmp[base + i].x >> 17], 1);
    __syncthreads();
    if (t < RPB) { scnt[t] = cursor[t]; srow[t] = cursor[t]; }
    __syncthreads();
    for (int off = 1; off < RPB; off <<= 1) {
        int add = (t >= off && t < RPB) ? srow[t - off] : 0;
        __syncthreads();
        if (t < RPB) srow[t] += add;
        __syncthreads();
    }
    if (t < RPB) { int ex = srow[t] - scnt[t]; srow[t] = ex; cursor[t] = ex; }
    __syncthreads();

    // scatter into LDS sorted by fine row (tmp L2-hot re-read)
    for (int i = t; i < n; i += 512) {
        int2 p = tmp[base + i];
        int rl = p.x >> 17;
        int pos = atomicAdd(&cursor[rl], 1);
        skv[pos] = make_int2(p.x & 0x1FFFF, p.y);
    }
    __syncthreads();

    // aggregate: wave w handles rows w, w+8, w+16, ...; lane owns feats {2l,2l+1}
    const unsigned* hb = h2 + lane;
#pragma unroll 1
    for (int rr = w; rr < RPB; rr += 8) {
        int gr = j * RPB + rr;                  // 1000*100 = exactly N_NODES
        int s = srow[rr];
        int end = s + scnt[rr];
        float ax = 0.f, ay = 0.f;

        int e = s;
        for (; e + 7 < end; e += 8) {
            int2 p0 = skv[e];
            int2 p1 = skv[e + 1];
            int2 p2 = skv[e + 2];
            int2 p3 = skv[e + 3];
            int2 p4 = skv[e + 4];
            int2 p5 = skv[e + 5];
            int2 p6 = skv[e + 6];
            int2 p7 = skv[e + 7];
            unsigned u0 = hb[(size_t)p0.x << 6];
            unsigned u1 = hb[(size_t)p1.x << 6];
            unsigned u2 = hb[(size_t)p2.x << 6];
            unsigned u3 = hb[(size_t)p3.x << 6];
            unsigned u4 = hb[(size_t)p4.x << 6];
            unsigned u5 = hb[(size_t)p5.x << 6];
            unsigned u6 = hb[(size_t)p6.x << 6];
            unsigned u7 = hb[(size_t)p7.x << 6];
            float v0 = __int_as_float(p0.y), v1 = __int_as_float(p1.y);
            float v2 = __int_as_float(p2.y), v3 = __int_as_float(p3.y);
            float v4 = __int_as_float(p4.y), v5 = __int_as_float(p5.y);
            float v6 = __int_as_float(p6.y), v7 = __int_as_float(p7.y);
            ax = fmaf(v0, __uint_as_float(u0 << 16), ax);
            ay = fmaf(v0, __uint_as_float(u0 & 0xFFFF0000u), ay);
            ax = fmaf(v1, __uint_as_float(u1 << 16), ax);
            ay = fmaf(v1, __uint_as_float(u1 & 0xFFFF0000u), ay);
            ax = fmaf(v2, __uint_as_float(u2 << 16), ax);
            ay = fmaf(v2, __uint_as_float(u2 & 0xFFFF0000u), ay);
            ax = fmaf(v3, __uint_as_float(u3 << 16), ax);
            ay = fmaf(v3, __uint_as_float(u3 & 0xFFFF0000u), ay);
            ax = fmaf(v4, __uint_as_float(u4 << 16), ax);
            ay = fmaf(v4, __uint_as_float(u4 & 0xFFFF0000u), ay);
            ax = fmaf(v5, __uint_as_float(u5 << 16), ax);
            ay = fmaf(v5, __uint_as_float(u5 & 0xFFFF0000u), ay);
            ax = fmaf(v6, __uint_as_float(u6 << 16), ax);
            ay = fmaf(v6, __uint_as_float(u6 & 0xFFFF0000u), ay);
            ax = fmaf(v7, __uint_as_float(u7 << 16), ax);
            ay = fmaf(v7, __uint_as_float(u7 & 0xFFFF0000u), ay);
        }
        for (; e < end; ++e) {
            int2 p0 = skv[e];
            unsigned u0 = hb[(size_t)p0.x << 6];
            float v0 = __int_as_float(p0.y);
            ax = fmaf(v0, __uint_as_float(u0 << 16), ax);
            ay = fmaf(v0, __uint_as_float(u0 & 0xFFFF0000u), ay);
        }

        float2 bb = *(const float2*)(bias + lane * 2);
        *(float2*)(out + (size_t)gr * OUT_F + lane * 2) =
            make_float2(ax + bb.x, ay + bb.y);
    }
}

// -------------------- launch --------------------
extern "C" void kernel_launch(void* const* d_in, const int* in_sizes, int n_in,
                              void* d_out, int out_size, void* d_ws, size_t ws_size,
                              hipStream_t stream)
{
    const float* x     = (const float*)d_in[0];
    const int*   erow  = (const int*)d_in[1];
    const int*   ecol  = (const int*)d_in[2];
    const float* eval_ = (const float*)d_in[3];
    const float* w     = (const float*)d_in[4];
    const float* bias  = (const float*)d_in[5];
    float*       out   = (float*)d_out;

    // workspace layout (bytes):
    //   h (bf16):    0          .. 25,600,000
    //   tmp:         25,600,000 .. 51,200,000
    //   cntmat:      51,200,000 .. 54,784,000   (896 x 1000 int)
    //   blockbase:   54,784,000 .. 58,368,000
    //   tot:         58,368,000 .. 58,372,000
    //   bucket_base: 58,372,000 .. 58,376,004 -> pad 58,376,064 (1001 int)
    //   wbfF:        58,376,064 .. 58,441,600   (~58.4 MB)
    char* ws = (char*)d_ws;
    unsigned short* h           = (unsigned short*)(ws);
    int2*           tmp         = (int2*)(ws + 25600000);
    int*            cntmat      = (int*)(ws + 51200000);
    int*            blockbase   = (int*)(ws + 54784000);
    int*            tot         = (int*)(ws + 58368000);
    int*            bucket_base = (int*)(ws + 58372000);
    uint4*          wbfF        = (uint4*)(ws + 58376064);

    // 1) w -> frag-ordered bf16  ||  coarse histogram (both input-only)
    hipLaunchKernelGGL(conv_hist_kernel, dim3(CONV_BLOCKS + NBC), dim3(256), 0, stream,
                       w, wbfF, erow, cntmat);

    // 2) scans
    hipLaunchKernelGGL(pass_b_kernel, dim3(NBIN), dim3(256), 0, stream,
                       cntmat, blockbase, tot);
    hipLaunchKernelGGL(pass_b2_kernel, dim3(1), dim3(512), 0, stream, tot, bucket_base);

    // 3) GEMM (needs wbfF)  ||  counting-sort scatter (needs scans) — independent
    hipLaunchKernelGGL(gemm_passc_kernel, dim3(GEMM_BLOCKS + NBC), dim3(256), 0, stream,
                       x, wbfF, h, erow, ecol, eval_, cntmat, blockbase,
                       bucket_base, tmp);

    // 4) fused fine-sort + aggregate + bias (needs h and tmp)
    hipLaunchKernelGGL(fused_da_kernel, dim3(NBIN), dim3(512), 0, stream,
                       tmp, bucket_base, (const unsigned*)h, bias, out);
}